// Round 1
// baseline (1190.127 us; speedup 1.0000x reference)
//
#include <hip/hip_runtime.h>

// Problem constants (fixed by the reference setup_inputs).
constexpr int B_ = 1024;
constexpr int S_ = 200;
constexpr int Q_ = 512;
constexpr int TQ = 2 * Q_;              // 1024 floats per batch row
constexpr int ROWS = B_ * (S_ - 1);     // 203,776 (b, t=i+1) rows we must scan

// One wave (64 lanes) scans one batch row (4 KB) for its single nonzero,
// gathers the corresponding pred element, accumulates -loglik locally.
__global__ __launch_bounds__(256, 4) void lossFunc_kernel(
    const float* __restrict__ pred,    // [B, S, Q]
    const float* __restrict__ batch,   // [B, S, 2Q]
    float* __restrict__ out)           // [1], pre-zeroed
{
    const int lane         = threadIdx.x & 63;
    const int waveInBlock  = threadIdx.x >> 6;
    const int wavesPerBlk  = blockDim.x >> 6;
    const int globalWave   = blockIdx.x * wavesPerBlk + waveInBlock;
    const int numWaves     = gridDim.x * wavesPerBlk;

    float acc = 0.0f;

    for (int r = globalWave; r < ROWS; r += numWaves) {
        const int b = r / (S_ - 1);
        const int i = r - b * (S_ - 1);   // 0 .. S-2
        const int t = i + 1;              // batch step whose one-hot we need

        const float4* row =
            (const float4*)(batch + ((size_t)b * S_ + t) * TQ);

        // 4 chunks of 1 KB each: lane reads float4 at index c*64 + lane.
        int j = -1;
        #pragma unroll
        for (int c = 0; c < 4; ++c) {
            const int f4idx = c * 64 + lane;
            const float4 v = row[f4idx];
            const int base = f4idx * 4;
            if (v.x != 0.0f) j = base + 0;
            if (v.y != 0.0f) j = base + 1;
            if (v.z != 0.0f) j = base + 2;
            if (v.w != 0.0f) j = base + 3;
        }

        // Exactly one lane (at most) found the nonzero.
        if (j >= 0) {
            const bool corr = (j < Q_);
            const int  q    = corr ? j : (j - Q_);
            const float p   = pred[((size_t)b * S_ + i) * Q_ + q];
            if (p > 0.0f) {
                // a=1 -> log(p); a=0 -> log(1-p). Accumulate negative ll.
                acc -= corr ? logf(p) : logf(1.0f - p);
            }
        }
    }

    // Wave reduction (64 lanes).
    #pragma unroll
    for (int off = 32; off > 0; off >>= 1)
        acc += __shfl_down(acc, off, 64);

    __shared__ float waveSums[4];
    if (lane == 0) waveSums[waveInBlock] = acc;
    __syncthreads();

    if (threadIdx.x == 0) {
        float s = 0.0f;
        for (int w = 0; w < wavesPerBlk; ++w) s += waveSums[w];
        atomicAdd(out, s);
    }
}

extern "C" void kernel_launch(void* const* d_in, const int* in_sizes, int n_in,
                              void* d_out, int out_size, void* d_ws, size_t ws_size,
                              hipStream_t stream) {
    const float* pred  = (const float*)d_in[0];
    const float* batch = (const float*)d_in[1];
    float* out = (float*)d_out;

    // Harness poisons d_out to 0xAA before each call — zero it (capture-safe).
    hipMemsetAsync(out, 0, sizeof(float), stream);

    const int blockSize = 256;            // 4 waves/block
    const int gridSize  = 2048;           // 8192 waves, ~25 rows each
    lossFunc_kernel<<<gridSize, blockSize, 0, stream>>>(pred, batch, out);
}

// Round 2
// 1187.264 us; speedup vs baseline: 1.0024x; 1.0024x over previous
//
#include <hip/hip_runtime.h>

// Problem constants (fixed by the reference setup_inputs).
constexpr int B_ = 1024;
constexpr int S_ = 200;
constexpr int Q_ = 512;
constexpr int TQ = 2 * Q_;              // 1024 floats per batch row
constexpr int ROWS = B_ * (S_ - 1);     // 203,776 (b, t=i+1) rows to scan

constexpr int BLOCK = 256;              // 4 waves/block
constexpr int GRID  = 2048;
constexpr int WAVES = GRID * (BLOCK / 64);   // 8192 waves, ~25 rows each
constexpr int STEP_B = WAVES / (S_ - 1);     // 41
constexpr int STEP_I = WAVES % (S_ - 1);     // 33

// One wave scans one 4 KB batch row for its single nonzero (one-hot),
// gathers pred[b, i, q] and accumulates the negative log-likelihood.
// Next row's loads are issued BEFORE the current row's dependent gather
// so the ~900-cycle HBM latency is always overlapped.
__global__ __launch_bounds__(BLOCK, 4) void lossFunc_kernel(
    const float* __restrict__ pred,    // [B, S, Q]
    const float* __restrict__ batch,   // [B, S, 2Q]
    float* __restrict__ out)           // [1], pre-zeroed
{
    const int lane = threadIdx.x & 63;
    const int wid  = threadIdx.x >> 6;
    const int gw   = blockIdx.x * (BLOCK / 64) + wid;

    int r = gw;
    int b = r / (S_ - 1);               // one division per kernel, then carry-step
    int i = r - b * (S_ - 1);           // 0 .. S-2; batch step is t = i+1

    float acc = 0.0f;

    if (r < ROWS) {
        // Prefetch first row: 4 float4 per lane = 4 KB per wave, coalesced.
        const float4* row = (const float4*)(batch + ((size_t)b * S_ + (i + 1)) * TQ);
        float4 v0 = row[lane];
        float4 v1 = row[64 + lane];
        float4 v2 = row[128 + lane];
        float4 v3 = row[192 + lane];

        while (true) {
            // --- issue next row's loads first (overlap with scan+gather) ---
            const int rn = r + WAVES;
            int bn = b + STEP_B;
            int in_ = i + STEP_I;
            if (in_ >= S_ - 1) { in_ -= (S_ - 1); bn += 1; }
            const bool more = (rn < ROWS);
            float4 n0 = v0, n1 = v1, n2 = v2, n3 = v3;
            if (more) {
                const float4* nrow =
                    (const float4*)(batch + ((size_t)bn * S_ + (in_ + 1)) * TQ);
                n0 = nrow[lane];
                n1 = nrow[64 + lane];
                n2 = nrow[128 + lane];
                n3 = nrow[192 + lane];
            }

            // --- scan current row for the one-hot position ---
            int j = -1;
            {
                const int e0 = lane * 4;
                if (v0.x != 0.0f) j = e0 + 0;
                if (v0.y != 0.0f) j = e0 + 1;
                if (v0.z != 0.0f) j = e0 + 2;
                if (v0.w != 0.0f) j = e0 + 3;
                const int e1 = 256 + lane * 4;
                if (v1.x != 0.0f) j = e1 + 0;
                if (v1.y != 0.0f) j = e1 + 1;
                if (v1.z != 0.0f) j = e1 + 2;
                if (v1.w != 0.0f) j = e1 + 3;
                const int e2 = 512 + lane * 4;
                if (v2.x != 0.0f) j = e2 + 0;
                if (v2.y != 0.0f) j = e2 + 1;
                if (v2.z != 0.0f) j = e2 + 2;
                if (v2.w != 0.0f) j = e2 + 3;
                const int e3 = 768 + lane * 4;
                if (v3.x != 0.0f) j = e3 + 0;
                if (v3.y != 0.0f) j = e3 + 1;
                if (v3.z != 0.0f) j = e3 + 2;
                if (v3.w != 0.0f) j = e3 + 3;
            }

            // --- exactly one lane (at most) holds the nonzero ---
            if (j >= 0) {
                const bool corr = (j < Q_);
                const int  q    = corr ? j : (j - Q_);
                const float p   = pred[((size_t)b * S_ + i) * Q_ + q];
                if (p > 0.0f) {
                    acc -= corr ? __logf(p) : __logf(1.0f - p);
                }
            }

            if (!more) break;
            v0 = n0; v1 = n1; v2 = n2; v3 = n3;
            r = rn; b = bn; i = in_;
        }
    }

    // Wave reduction (64 lanes).
    #pragma unroll
    for (int off = 32; off > 0; off >>= 1)
        acc += __shfl_down(acc, off, 64);

    __shared__ float waveSums[BLOCK / 64];
    if (lane == 0) waveSums[wid] = acc;
    __syncthreads();

    if (threadIdx.x == 0) {
        float s = 0.0f;
        #pragma unroll
        for (int w = 0; w < BLOCK / 64; ++w) s += waveSums[w];
        atomicAdd(out, s);
    }
}

extern "C" void kernel_launch(void* const* d_in, const int* in_sizes, int n_in,
                              void* d_out, int out_size, void* d_ws, size_t ws_size,
                              hipStream_t stream) {
    const float* pred  = (const float*)d_in[0];
    const float* batch = (const float*)d_in[1];
    float* out = (float*)d_out;

    // Harness poisons d_out to 0xAA before each call — zero it (capture-safe).
    hipMemsetAsync(out, 0, sizeof(float), stream);

    lossFunc_kernel<<<GRID, BLOCK, 0, stream>>>(pred, batch, out);
}

// Round 3
// 1165.566 us; speedup vs baseline: 1.0211x; 1.0186x over previous
//
#include <hip/hip_runtime.h>

// Problem constants (fixed by the reference setup_inputs).
constexpr int B_ = 1024;
constexpr int S_ = 200;
constexpr int Q_ = 512;
constexpr int TQ = 2 * Q_;              // 1024 floats per batch row
constexpr int ROWS = B_ * (S_ - 1);     // 203,776 (b, t=i+1) rows to scan

constexpr int BLOCK = 256;              // 4 waves/block
constexpr int GRID  = 2048;
constexpr int WAVES = GRID * (BLOCK / 64);   // 8192 waves, ~25 rows each

// One wave handles one batch row. The row is one-hot: exactly one nonzero
// among 1024 floats. 60% of the time (correct=1) it is in the first half —
// read the first 2 KB always, and only fetch the second 2 KB when the wave
// found nothing (wave-uniform ballot branch). Expected traffic: 2.8 KB/row
// instead of 4 KB (~30% less HBM fetch on the dominant stream).
__global__ __launch_bounds__(BLOCK, 8) void lossFunc_kernel(
    const float* __restrict__ pred,    // [B, S, Q]
    const float* __restrict__ batch,   // [B, S, 2Q]
    float* __restrict__ out)           // [1], pre-zeroed
{
    const int lane = threadIdx.x & 63;
    const int wid  = threadIdx.x >> 6;
    const int gw   = blockIdx.x * (BLOCK / 64) + wid;

    float acc = 0.0f;

    for (int r = gw; r < ROWS; r += WAVES) {
        const int b = r / (S_ - 1);
        const int i = r - b * (S_ - 1);   // 0 .. S-2; batch step t = i+1

        const float4* row =
            (const float4*)(batch + ((size_t)b * S_ + (i + 1)) * TQ);

        // First half: 2 KB = 128 float4, 2 per lane. Coalesced.
        const float4 v0 = row[lane];
        const float4 v1 = row[64 + lane];

        int j = -1;
        {
            const int e0 = lane * 4;
            if (v0.x != 0.0f) j = e0 + 0;
            if (v0.y != 0.0f) j = e0 + 1;
            if (v0.z != 0.0f) j = e0 + 2;
            if (v0.w != 0.0f) j = e0 + 3;
            const int e1 = 256 + lane * 4;
            if (v1.x != 0.0f) j = e1 + 0;
            if (v1.y != 0.0f) j = e1 + 1;
            if (v1.z != 0.0f) j = e1 + 2;
            if (v1.w != 0.0f) j = e1 + 3;
        }

        // Wave-uniform: did anyone find it in the first (correct) half?
        if (__ballot(j >= 0) == 0ULL) {
            // No — fetch the second half (incorrect-answer block).
            const float4 v2 = row[128 + lane];
            const float4 v3 = row[192 + lane];
            const int e2 = 512 + lane * 4;
            if (v2.x != 0.0f) j = e2 + 0;
            if (v2.y != 0.0f) j = e2 + 1;
            if (v2.z != 0.0f) j = e2 + 2;
            if (v2.w != 0.0f) j = e2 + 3;
            const int e3 = 768 + lane * 4;
            if (v3.x != 0.0f) j = e3 + 0;
            if (v3.y != 0.0f) j = e3 + 1;
            if (v3.z != 0.0f) j = e3 + 2;
            if (v3.w != 0.0f) j = e3 + 3;
        }

        // Exactly one lane holds the nonzero.
        if (j >= 0) {
            const bool corr = (j < Q_);
            const int  q    = corr ? j : (j - Q_);
            const float p   = pred[((size_t)b * S_ + i) * Q_ + q];
            if (p > 0.0f) {
                acc -= corr ? __logf(p) : __logf(1.0f - p);
            }
        }
    }

    // Wave reduction (64 lanes).
    #pragma unroll
    for (int off = 32; off > 0; off >>= 1)
        acc += __shfl_down(acc, off, 64);

    __shared__ float waveSums[BLOCK / 64];
    if (lane == 0) waveSums[wid] = acc;
    __syncthreads();

    if (threadIdx.x == 0) {
        float s = 0.0f;
        #pragma unroll
        for (int w = 0; w < BLOCK / 64; ++w) s += waveSums[w];
        atomicAdd(out, s);
    }
}

extern "C" void kernel_launch(void* const* d_in, const int* in_sizes, int n_in,
                              void* d_out, int out_size, void* d_ws, size_t ws_size,
                              hipStream_t stream) {
    const float* pred  = (const float*)d_in[0];
    const float* batch = (const float*)d_in[1];
    float* out = (float*)d_out;

    // Harness poisons d_out to 0xAA before each call — zero it (capture-safe).
    hipMemsetAsync(out, 0, sizeof(float), stream);

    lossFunc_kernel<<<GRID, BLOCK, 0, stream>>>(pred, batch, out);
}